// Round 1
// baseline (419.729 us; speedup 1.0000x reference)
//
#include <hip/hip_runtime.h>
#include <stdint.h>

typedef unsigned short u16;
typedef short bf16x8 __attribute__((ext_vector_type(8)));
typedef float f32x4 __attribute__((ext_vector_type(4)));
typedef u16 u16x8 __attribute__((ext_vector_type(8)));
typedef u16 u16x4 __attribute__((ext_vector_type(4)));

#define NB 8
#define NS 1024
#define NH 16
#define NDH 64
#define ND 1024

__device__ __forceinline__ u16 f2b(float x){
  unsigned u = __float_as_uint(x);
  u += 0x7FFFu + ((u >> 16) & 1u);          // RNE
  return (u16)(u >> 16);
}
__device__ __forceinline__ float b2f(u16 h){ return __uint_as_float(((unsigned)h) << 16); }

// ---------------- cast f32 -> bf16 (n multiple of 8) ----------------
__global__ void cast_f32_bf16(const float* __restrict__ in, u16* __restrict__ out, long n){
  long i = ((long)blockIdx.x * blockDim.x + threadIdx.x) * 8;
  if (i + 8 <= n){
    float4 a = *(const float4*)&in[i];
    float4 b = *(const float4*)&in[i + 4];
    u16x8 o;
    o[0]=f2b(a.x); o[1]=f2b(a.y); o[2]=f2b(a.z); o[3]=f2b(a.w);
    o[4]=f2b(b.x); o[5]=f2b(b.y); o[6]=f2b(b.z); o[7]=f2b(b.w);
    *(u16x8*)&out[i] = o;
  }
}

// ---------------- transpose W (fp32 [k][n]) -> wt bf16 [p*1024+n][k] ----------------
__global__ void transpose_w(const float* __restrict__ Wq, const float* __restrict__ Wk,
                            const float* __restrict__ Wv, u16* __restrict__ wt){
  __shared__ float tile[64][65];
  int p = blockIdx.z;
  const float* W = (p == 0) ? Wq : ((p == 1) ? Wk : Wv);
  int n0 = blockIdx.x * 64, k0 = blockIdx.y * 64;
  int t = threadIdx.x;
  int row = t >> 2, cb = (t & 3) * 16;
  #pragma unroll
  for (int cc = 0; cc < 4; ++cc){
    float4 v = *(const float4*)&W[(size_t)(k0 + row) * ND + n0 + cb + cc * 4];
    tile[row][cb + cc*4 + 0] = v.x; tile[row][cb + cc*4 + 1] = v.y;
    tile[row][cb + cc*4 + 2] = v.z; tile[row][cb + cc*4 + 3] = v.w;
  }
  __syncthreads();
  u16x8 o0, o1;
  #pragma unroll
  for (int kk = 0; kk < 8; ++kk) o0[kk] = f2b(tile[cb + kk][row]);
  #pragma unroll
  for (int kk = 0; kk < 8; ++kk) o1[kk] = f2b(tile[cb + 8 + kk][row]);
  size_t ob = ((size_t)(p * ND + n0 + row)) * ND + k0 + cb;
  *(u16x8*)&wt[ob]     = o0;
  *(u16x8*)&wt[ob + 8] = o1;
}

// ---------------- QKV GEMM: [8192,1024]bf16 @ Wt^T -> q,k [B,S,D] bf16 ; v transposed [BH,DH,S] ----------------
__global__ __launch_bounds__(256) void qkv_gemm(
    const u16* __restrict__ hsb, const u16* __restrict__ wtb,
    const float* __restrict__ bq, const float* __restrict__ bk, const float* __restrict__ bv,
    u16* __restrict__ qb, u16* __restrict__ kb, u16* __restrict__ vt){
  __shared__ __attribute__((aligned(16))) u16 Al[128 * 32];
  __shared__ __attribute__((aligned(16))) u16 Bl[128 * 32];
  int t = threadIdx.x;
  int lane = t & 63, w = t >> 6;
  int li = lane & 15, g = lane >> 4;
  int m0 = blockIdx.y * 128, n0 = blockIdx.x * 128;
  int wm = (w >> 1) * 64, wn = (w & 1) * 64;
  f32x4 acc[4][4];
  #pragma unroll
  for (int a = 0; a < 4; ++a)
    #pragma unroll
    for (int b = 0; b < 4; ++b){ f32x4 z = {0.f,0.f,0.f,0.f}; acc[a][b] = z; }

  for (int kt = 0; kt < 32; ++kt){
    __syncthreads();
    #pragma unroll
    for (int ph = 0; ph < 2; ++ph){
      int c = ph * 256 + t;            // chunk 0..511 (16B each)
      int row = c >> 2, ch = c & 3;
      const u16* ga = &hsb[(size_t)(m0 + row) * ND + kt * 32 + ch * 8];
      __builtin_amdgcn_global_load_lds((const __attribute__((address_space(1))) void*)ga,
          (__attribute__((address_space(3))) void*)&Al[(ph * 256 + w * 64) * 8], 16, 0, 0);
      const u16* gb = &wtb[(size_t)(n0 + row) * ND + kt * 32 + ch * 8];
      __builtin_amdgcn_global_load_lds((const __attribute__((address_space(1))) void*)gb,
          (__attribute__((address_space(3))) void*)&Bl[(ph * 256 + w * 64) * 8], 16, 0, 0);
    }
    asm volatile("s_waitcnt vmcnt(0)" ::: "memory");
    __syncthreads();
    bf16x8 af[4], bfr[4];
    #pragma unroll
    for (int mt = 0; mt < 4; ++mt)
      af[mt] = *(const bf16x8*)&Al[(wm + mt * 16 + li) * 32 + g * 8];
    #pragma unroll
    for (int nt = 0; nt < 4; ++nt)
      bfr[nt] = *(const bf16x8*)&Bl[(wn + nt * 16 + li) * 32 + g * 8];
    #pragma unroll
    for (int mt = 0; mt < 4; ++mt)
      #pragma unroll
      for (int nt = 0; nt < 4; ++nt)
        acc[mt][nt] = __builtin_amdgcn_mfma_f32_16x16x32_bf16(af[mt], bfr[nt], acc[mt][nt], 0, 0, 0);
  }

  int proj = n0 >> 10;
  const float* bias = (proj == 0) ? bq : ((proj == 1) ? bk : bv);
  #pragma unroll
  for (int nt = 0; nt < 4; ++nt){
    int n = n0 + wn + nt * 16 + li;
    int nc = n & 1023;
    float bv_ = bias[nc];
    #pragma unroll
    for (int mt = 0; mt < 4; ++mt){
      #pragma unroll
      for (int r = 0; r < 4; ++r){
        int m = m0 + wm + mt * 16 + g * 4 + r;
        u16 hv = f2b(acc[mt][nt][r] + bv_);
        if (proj == 0)      qb[(size_t)m * ND + nc] = hv;
        else if (proj == 1) kb[(size_t)m * ND + nc] = hv;
        else {
          int bb = m >> 10, s = m & 1023;
          int hh = nc >> 6, dh = nc & 63;
          vt[((size_t)(bb * NH + hh) * NDH + dh) * NS + s] = hv;
        }
      }
    }
  }
}

// ---------------- fused flash attention with relative_key_query bias ----------------
// block: 256 thr (4 waves); Q-tile 64 rows (16/wave); K-tile 64. grid (16 ltiles, 128 bh)
__global__ __launch_bounds__(256) void attn(
    const u16* __restrict__ qb, const u16* __restrict__ kb,
    const u16* __restrict__ vt, const u16* __restrict__ eb,
    const float* __restrict__ mask, float* __restrict__ out){
  // padded rows: 64+8 ushorts -> 144B stride (16B-aligned, ~2-way bank alias max)
  __shared__ __attribute__((aligned(16))) u16 k_lds[64 * 72];
  __shared__ __attribute__((aligned(16))) u16 v_lds[64 * 72];
  __shared__ __attribute__((aligned(16))) u16 e_lds[128 * 72];
  __shared__ __attribute__((aligned(16))) u16 u2_lds[128 * 72];  // U2t[t][i]; rows also reused as P
  __shared__ __attribute__((aligned(16))) u16 w2_lds[128 * 72];  // W2t[t][j]
  int t = threadIdx.x, lane = t & 63, w = t >> 6;
  int li = lane & 15, g = lane >> 4;
  int lt = blockIdx.x, bh = blockIdx.y;
  int b = bh >> 4, h = bh & 15;
  int l0 = lt * 64;

  // Q A-frags (16 rows per wave), held in registers for all 16 K-tiles
  bf16x8 qf[2];
  {
    size_t qoff = ((size_t)(b * NS + l0 + w * 16 + li)) * ND + h * NDH;
    qf[0] = *(const bf16x8*)&qb[qoff + 0 + g * 8];
    qf[1] = *(const bf16x8*)&qb[qoff + 32 + g * 8];
  }
  f32x4 oacc[4];
  #pragma unroll
  for (int i = 0; i < 4; ++i){ f32x4 z = {0.f,0.f,0.f,0.f}; oacc[i] = z; }
  float mold[4] = {-1e30f, -1e30f, -1e30f, -1e30f};
  float lsum[4] = {0.f, 0.f, 0.f, 0.f};

  for (int kt2 = 0; kt2 < 16; ++kt2){
    int r0 = kt2 * 64;
    int ebase = l0 - r0 + 960;                 // t index: i_blk - j + 63 in [0,126]
    __syncthreads();                           // b0: prev iter PV done before restage
    {
      u16x8 rk[2], rv[2], re[4];
      #pragma unroll
      for (int ph = 0; ph < 2; ++ph){
        int c = ph * 256 + t, row = c >> 3, ch = c & 7;
        rk[ph] = *(const u16x8*)&kb[((size_t)(b * NS + r0 + row)) * ND + h * NDH + ch * 8];
        rv[ph] = *(const u16x8*)&vt[((size_t)(bh * NDH + row)) * NS + r0 + ch * 8];
      }
      #pragma unroll
      for (int ph = 0; ph < 4; ++ph){
        int c = ph * 256 + t, row = c >> 3, ch = c & 7;
        int er = ebase + row; er = er > 2046 ? 2046 : er;   // row 127 is pad, never gathered
        re[ph] = *(const u16x8*)&eb[(size_t)er * NDH + ch * 8];
      }
      #pragma unroll
      for (int ph = 0; ph < 2; ++ph){
        int c = ph * 256 + t, row = c >> 3, ch = c & 7;
        *(u16x8*)&k_lds[row * 72 + ch * 8] = rk[ph];
        *(u16x8*)&v_lds[row * 72 + ch * 8] = rv[ph];
      }
      #pragma unroll
      for (int ph = 0; ph < 4; ++ph){
        int c = ph * 256 + t, row = c >> 3, ch = c & 7;
        *(u16x8*)&e_lds[row * 72 + ch * 8] = re[ph];
      }
    }
    __syncthreads();                           // b1: tiles staged

    // k A-frags (this wave's 16 j rows) for W2
    bf16x8 kf[2];
    kf[0] = *(const bf16x8*)&k_lds[(w * 16 + li) * 72 + 0 + g * 8];
    kf[1] = *(const bf16x8*)&k_lds[(w * 16 + li) * 72 + 32 + g * 8];

    // U2t[t][i] = q_i . e[t] ; W2t[t][j] = k_j . e[t]
    #pragma unroll
    for (int nt = 0; nt < 8; ++nt){
      f32x4 ua = {0.f,0.f,0.f,0.f}, wa = {0.f,0.f,0.f,0.f};
      #pragma unroll
      for (int ks = 0; ks < 2; ++ks){
        bf16x8 ef = *(const bf16x8*)&e_lds[(nt * 16 + li) * 72 + ks * 32 + g * 8];
        ua = __builtin_amdgcn_mfma_f32_16x16x32_bf16(qf[ks], ef, ua, 0, 0, 0);
        wa = __builtin_amdgcn_mfma_f32_16x16x32_bf16(kf[ks], ef, wa, 0, 0, 0);
      }
      // C layout: lane holds col t=nt*16+li, rows 4g..4g+3 -> pack 4 consecutive i/j
      u16x4 up, wp;
      #pragma unroll
      for (int r = 0; r < 4; ++r){ up[r] = f2b(ua[r]); wp[r] = f2b(wa[r]); }
      *(u16x4*)&u2_lds[(nt * 16 + li) * 72 + w * 16 + g * 4] = up;
      *(u16x4*)&w2_lds[(nt * 16 + li) * 72 + w * 16 + g * 4] = wp;
    }

    // QK^T for this wave's 16 q-rows x 64 cols
    f32x4 sacc[4];
    #pragma unroll
    for (int jt = 0; jt < 4; ++jt){
      f32x4 z = {0.f,0.f,0.f,0.f}; sacc[jt] = z;
      #pragma unroll
      for (int ks = 0; ks < 2; ++ks){
        bf16x8 kbf = *(const bf16x8*)&k_lds[(jt * 16 + li) * 72 + ks * 32 + g * 8];
        sacc[jt] = __builtin_amdgcn_mfma_f32_16x16x32_bf16(qf[ks], kbf, sacc[jt], 0, 0, 0);
      }
    }
    __syncthreads();                           // b2: U2/W2 visible to all waves

    // gather diag bias + assemble scores
    float sv[4][4];
    #pragma unroll
    for (int jt = 0; jt < 4; ++jt){
      int j = jt * 16 + li;
      float mk = mask[b * NS + r0 + j];
      #pragma unroll
      for (int r = 0; r < 4; ++r){
        int ib = w * 16 + g * 4 + r;
        int tt = ib - j + 63;
        float u  = b2f(u2_lds[tt * 72 + ib]);
        float ww = b2f(w2_lds[tt * 72 + j]);
        sv[jt][r] = sacc[jt][r] * 0.125f + u + ww + mk;
      }
    }

    // online softmax (rows live in 16-lane groups)
    float rmax[4], rsum[4];
    #pragma unroll
    for (int r = 0; r < 4; ++r)
      rmax[r] = fmaxf(fmaxf(sv[0][r], sv[1][r]), fmaxf(sv[2][r], sv[3][r]));
    #pragma unroll
    for (int xm = 1; xm <= 8; xm <<= 1)
      #pragma unroll
      for (int r = 0; r < 4; ++r)
        rmax[r] = fmaxf(rmax[r], __shfl_xor(rmax[r], xm));
    float mnew[4], fac[4];
    #pragma unroll
    for (int r = 0; r < 4; ++r){
      mnew[r] = fmaxf(mold[r], rmax[r]);
      fac[r]  = __expf(mold[r] - mnew[r]);
    }
    float pr[4][4];
    #pragma unroll
    for (int r = 0; r < 4; ++r) rsum[r] = 0.f;
    #pragma unroll
    for (int jt = 0; jt < 4; ++jt)
      #pragma unroll
      for (int r = 0; r < 4; ++r){
        pr[jt][r] = __expf(sv[jt][r] - mnew[r]);
        rsum[r] += pr[jt][r];
      }
    #pragma unroll
    for (int xm = 1; xm <= 8; xm <<= 1)
      #pragma unroll
      for (int r = 0; r < 4; ++r)
        rsum[r] += __shfl_xor(rsum[r], xm);
    #pragma unroll
    for (int r = 0; r < 4; ++r){
      lsum[r] = lsum[r] * fac[r] + rsum[r];
      mold[r] = mnew[r];
    }
    #pragma unroll
    for (int nt2 = 0; nt2 < 4; ++nt2)
      #pragma unroll
      for (int r = 0; r < 4; ++r)
        oacc[nt2][r] *= fac[r];

    __syncthreads();                           // b3: all gathers done; u2 rows reusable as P
    u16* p_w = &u2_lds[(w * 16) * 72];         // this wave's private P strip [16][72]
    #pragma unroll
    for (int jt = 0; jt < 4; ++jt)
      #pragma unroll
      for (int r = 0; r < 4; ++r)
        p_w[(g * 4 + r) * 72 + jt * 16 + li] = f2b(pr[jt][r]);

    // PV: O += P @ V   (A=P rows i, B=V^T[dh][j] from v_lds)
    #pragma unroll
    for (int ks = 0; ks < 2; ++ks){
      bf16x8 pf = *(const bf16x8*)&p_w[li * 72 + ks * 32 + g * 8];
      #pragma unroll
      for (int nt2 = 0; nt2 < 4; ++nt2){
        bf16x8 vf = *(const bf16x8*)&v_lds[(nt2 * 16 + li) * 72 + ks * 32 + g * 8];
        oacc[nt2] = __builtin_amdgcn_mfma_f32_16x16x32_bf16(pf, vf, oacc[nt2], 0, 0, 0);
      }
    }
  }

  // epilogue: O / lsum -> out fp32 [B,S,D]
  #pragma unroll
  for (int nt2 = 0; nt2 < 4; ++nt2)
    #pragma unroll
    for (int r = 0; r < 4; ++r){
      int row = l0 + w * 16 + g * 4 + r;
      out[((size_t)(b * NS + row)) * ND + h * NDH + nt2 * 16 + li] = oacc[nt2][r] / lsum[r];
    }
}

extern "C" void kernel_launch(void* const* d_in, const int* in_sizes, int n_in,
                              void* d_out, int out_size, void* d_ws, size_t ws_size,
                              hipStream_t stream){
  (void)in_sizes; (void)n_in; (void)out_size; (void)ws_size;
  const float* hs   = (const float*)d_in[0];
  const float* mask = (const float*)d_in[1];
  const float* Wq   = (const float*)d_in[2];
  const float* bq   = (const float*)d_in[3];
  const float* Wk   = (const float*)d_in[4];
  const float* bk   = (const float*)d_in[5];
  const float* Wv   = (const float*)d_in[6];
  const float* bv   = (const float*)d_in[7];
  const float* de   = (const float*)d_in[8];
  float* out = (float*)d_out;
  char* ws = (char*)d_ws;

  u16* hsb = (u16*)(ws);                    // 16,777,216 B
  u16* wtb = (u16*)(ws + 16777216);         //  6,291,456 B
  u16* eb  = (u16*)(ws + 23068672);         //    262,016 B (+pad)
  u16* qb  = (u16*)(ws + 23330816);         // 16,777,216 B
  u16* kb  = (u16*)(ws + 40108032);         // 16,777,216 B
  u16* vt  = (u16*)(ws + 56885248);         // 16,777,216 B  -> total ~70.2 MB

  cast_f32_bf16<<<4096, 256, 0, stream>>>(hs, hsb, 8388608L);
  cast_f32_bf16<<<64, 256, 0, stream>>>(de, eb, 131008L);
  transpose_w<<<dim3(16, 16, 3), 256, 0, stream>>>(Wq, Wk, Wv, wtb);
  qkv_gemm<<<dim3(24, 64), 256, 0, stream>>>(hsb, wtb, bq, bk, bv, qb, kb, vt);
  attn<<<dim3(16, 128), 256, 0, stream>>>(qb, kb, vt, eb, mask, out);
}